// Round 2
// baseline (446.586 us; speedup 1.0000x reference)
//
#include <hip/hip_runtime.h>
#include <hip/hip_bf16.h>

// out[b,a,f] = relu( a < n_atoms[b] ? features[b,a,f] + res[0,b,a,f] + res[1,b,a,f] : 0 )
// B=256, A=128, F=1024, N_RES=2. Pure memory-bound elementwise fusion.
// One float4 per thread; blockDim=256 => one block-iteration == one (b,a) row
// (1024 floats), so n_atoms[b] is wave-uniform within the block.
// Masked rows skip ALL global reads (≈50% of rows) — only write zeros.

#define TOTAL4 (256LL * 128LL * 256LL)   // total float4 elements = 8,388,608

__global__ __launch_bounds__(256) void dense_block_end_kernel(
    const float4* __restrict__ feat,
    const float4* __restrict__ res,      // res[0] at offset 0, res[1] at offset TOTAL4
    const int*    __restrict__ ms,       // mol_slice, int32 view
    float4*       __restrict__ out)
{
    // Layout dispatch: int32 upload -> ms = {n0,1024,n1,1024,...} (stride 2);
    // raw int64 viewed as int32 -> ms = {n0,0,1024,0,n1,0,...} (stride 4).
    const int msStride = (ms[1] == 1024) ? 2 : 4;

    const long long gstride = (long long)gridDim.x * blockDim.x;
    for (long long i = (long long)blockIdx.x * blockDim.x + threadIdx.x;
         i < TOTAL4; i += gstride) {
        const int row = (int)(i >> 8);   // 256 float4 per row
        const int a   = row & 127;       // atom index
        const int b   = row >> 7;        // batch index
        const int n   = ms[msStride * b];

        float4 o;
        if (a < n) {
            const float4 f  = feat[i];
            const float4 r0 = res[i];
            const float4 r1 = res[i + TOTAL4];
            o.x = fmaxf(f.x + r0.x + r1.x, 0.0f);
            o.y = fmaxf(f.y + r0.y + r1.y, 0.0f);
            o.z = fmaxf(f.z + r0.z + r1.z, 0.0f);
            o.w = fmaxf(f.w + r0.w + r1.w, 0.0f);
        } else {
            o.x = 0.0f; o.y = 0.0f; o.z = 0.0f; o.w = 0.0f;
        }
        out[i] = o;
    }
}

extern "C" void kernel_launch(void* const* d_in, const int* in_sizes, int n_in,
                              void* d_out, int out_size, void* d_ws, size_t ws_size,
                              hipStream_t stream)
{
    const float4* feat = (const float4*)d_in[0];
    const float4* res  = (const float4*)d_in[1];
    const int*    ms   = (const int*)d_in[2];
    float4*       out  = (float4*)d_out;

    // Grid: cap at 2048 blocks (256 CUs x 8 blocks), grid-stride the rest.
    const int block = 256;
    const int grid  = 2048;
    dense_block_end_kernel<<<grid, block, 0, stream>>>(feat, res, ms, out);
}